// Round 13
// baseline (186.872 us; speedup 1.0000x reference)
//
#include <hip/hip_runtime.h>
#include <hip/hip_bf16.h>

typedef __attribute__((ext_vector_type(4))) float f32x4;
typedef __attribute__((ext_vector_type(8))) short bf16x8;
typedef __attribute__((ext_vector_type(4))) unsigned short u16x4;
typedef __attribute__((ext_vector_type(8))) unsigned short u16x8;

__device__ __forceinline__ unsigned short f2bf(float f) {
    unsigned int u = __builtin_bit_cast(unsigned int, f);
    u += 0x7fffu + ((u >> 16) & 1u);   // RNE; inputs finite
    return (unsigned short)(u >> 16);
}

// swizzle in ushort units: XOR bits 3..5 with bits 6..8 (involution)
#define SWZ(i) ((i) ^ ((((i) >> 6) & 7) << 3))

// ---------------- transpose+convert: W^T into tiled+swizzled bf16 ----------
__global__ void transpose_cvt(const float* __restrict__ src,
                              unsigned short* __restrict__ dst,
                              int rows, int cols) {
    int idx = blockIdx.x * 256 + threadIdx.x;     // idx = n*rows + k
    int n = idx / rows;
    int k = idx - n * rows;
    unsigned short v = f2bf(src[(size_t)k * cols + n]);
    int tile = (n >> 7) * (rows >> 6) + (k >> 6);
    dst[(size_t)tile * 8192 + SWZ((n & 127) * 64 + (k & 63))] = v;
}

// ---------------- small GEMM (K=512): BM=64, BN=128 (unchanged, R12) -------
template<int EPI>
__global__ __launch_bounds__(512, 4)
void gemm_small(const float* __restrict__ A, long lda,
                const unsigned short* __restrict__ Bt,
                int K,
                const float* __restrict__ epi, long lde,
                const float* __restrict__ bias,
                void* __restrict__ Dptr, long ldd) {
    __shared__ unsigned short sA[2][64 * 64];
    __shared__ unsigned short sB[2][128 * 64];

    const int t = threadIdx.x;
    const int l = t & 63;
    const int w = t >> 6;
    const int wm = w >> 2;
    const int wn = w & 3;

    int mt, nt;
    {
        int lin = blockIdx.y * gridDim.x + blockIdx.x;
        int xcd = lin & 7;
        int slot = lin >> 3;
        int ppx = gridDim.y >> 3;
        mt = xcd * ppx + slot / gridDim.x;
        nt = slot % gridDim.x;
    }
    const long m0 = (long)mt * 64;
    const long n0 = (long)nt * 128;
    const int KT = K >> 6;
    const unsigned short* Bblk = Bt + (size_t)nt * KT * 8192;

    f32x4 acc[2][2];
    #pragma unroll
    for (int m = 0; m < 2; ++m)
        #pragma unroll
        for (int n = 0; n < 2; ++n)
            acc[m][n] = {0.f, 0.f, 0.f, 0.f};

    f32x4 aX0, aX1, aY0, aY1;

    auto gll_B = [&](int kt, int buf) {
        const unsigned short* src = Bblk + (size_t)kt * 8192 + t * 8;
        #pragma unroll
        for (int r = 0; r < 2; ++r)
            __builtin_amdgcn_global_load_lds(
                (const __attribute__((address_space(1))) void*)(src + r * 4096),
                (__attribute__((address_space(3))) void*)&sB[buf][r * 4096 + w * 512],
                16, 0, 0);
    };

    auto load_A = [&](int kt, f32x4& a0, f32x4& a1) {
        const float* p0 = &A[(m0 + (t >> 4)) * lda + (long)kt * 64 + ((t & 15) << 2)];
        const float* p1 = p0 + 32 * lda;
        asm volatile("global_load_dwordx4 %0, %2, off\n\t"
                     "global_load_dwordx4 %1, %3, off"
                     : "=&v"(a0), "=&v"(a1)
                     : "v"(p0), "v"(p1)
                     : "memory");
    };

    auto write_A = [&](int buf, const f32x4& a0, const f32x4& a1) {
        int e0 = t * 4;
        u16x4 w0 = {f2bf(a0[0]), f2bf(a0[1]), f2bf(a0[2]), f2bf(a0[3])};
        *reinterpret_cast<u16x4*>(&sA[buf][SWZ(e0)]) = w0;
        int e1 = 2048 + t * 4;
        u16x4 w1 = {f2bf(a1[0]), f2bf(a1[1]), f2bf(a1[2]), f2bf(a1[3])};
        *reinterpret_cast<u16x4*>(&sA[buf][SWZ(e1)]) = w1;
    };

    auto compute = [&](int buf) {
        #pragma unroll
        for (int kk = 0; kk < 2; ++kk) {
            bf16x8 af[2], bfr[2];
            const int kb = kk * 32 + ((l >> 4) << 3);
            #pragma unroll
            for (int m = 0; m < 2; ++m) {
                int row = wm * 32 + m * 16 + (l & 15);
                af[m] = *reinterpret_cast<const bf16x8*>(&sA[buf][SWZ(row * 64 + kb)]);
            }
            #pragma unroll
            for (int n = 0; n < 2; ++n) {
                int col = wn * 32 + n * 16 + (l & 15);
                bfr[n] = *reinterpret_cast<const bf16x8*>(&sB[buf][SWZ(col * 64 + kb)]);
            }
            __builtin_amdgcn_s_setprio(1);
            #pragma unroll
            for (int m = 0; m < 2; ++m)
                #pragma unroll
                for (int n = 0; n < 2; ++n)
                    acc[m][n] = __builtin_amdgcn_mfma_f32_16x16x32_bf16(
                        af[m], bfr[n], acc[m][n], 0, 0, 0);
            __builtin_amdgcn_s_setprio(0);
        }
    };

    gll_B(0, 0);
    load_A(0, aX0, aX1);
    load_A(1, aY0, aY1);
    asm volatile("s_waitcnt vmcnt(2)" ::: "memory");
    __builtin_amdgcn_sched_barrier(0);
    write_A(0, aX0, aX1);
    asm volatile("s_waitcnt lgkmcnt(0)" ::: "memory");
    __builtin_amdgcn_s_barrier();
    __builtin_amdgcn_sched_barrier(0);

    const int nk = K >> 6;   // 8
    for (int p = 0; p + 2 < nk; p += 2) {
        gll_B(p + 1, 1);
        load_A(p + 2, aX0, aX1);
        compute(0);
        asm volatile("s_waitcnt vmcnt(4)" ::: "memory");
        __builtin_amdgcn_sched_barrier(0);
        write_A(1, aY0, aY1);
        asm volatile("s_waitcnt vmcnt(2) lgkmcnt(0)" ::: "memory");
        __builtin_amdgcn_s_barrier();
        __builtin_amdgcn_sched_barrier(0);

        gll_B(p + 2, 0);
        load_A(p + 3, aY0, aY1);
        compute(1);
        asm volatile("s_waitcnt vmcnt(4)" ::: "memory");
        __builtin_amdgcn_sched_barrier(0);
        write_A(0, aX0, aX1);
        asm volatile("s_waitcnt vmcnt(2) lgkmcnt(0)" ::: "memory");
        __builtin_amdgcn_s_barrier();
        __builtin_amdgcn_sched_barrier(0);
    }

    gll_B(nk - 1, 1);
    compute(0);
    asm volatile("s_waitcnt vmcnt(2)" ::: "memory");
    __builtin_amdgcn_sched_barrier(0);
    write_A(1, aY0, aY1);
    asm volatile("s_waitcnt vmcnt(0) lgkmcnt(0)" ::: "memory");
    __builtin_amdgcn_s_barrier();
    __builtin_amdgcn_sched_barrier(0);
    compute(1);

    const int jrow = (l >> 4) * 4;
    #pragma unroll
    for (int m = 0; m < 2; ++m) {
        const long row = m0 + wm * 32 + m * 16 + jrow;
        #pragma unroll
        for (int n = 0; n < 2; ++n) {
            const long col = n0 + wn * 32 + n * 16 + (l & 15);
            f32x4 v = acc[m][n];
            if constexpr (EPI == 0) {
                u16x4 o;
                #pragma unroll
                for (int j = 0; j < 4; ++j)
                    o[j] = f2bf(v[j] + epi[(row + j) * lde + col]);
                // Tbt: tile = (col>>8)*256 + (row>>5); e = (col&255)*32 + (row&31)
                int tile = ((int)col >> 8) * 256 + ((int)row >> 5);
                int e = ((int)col & 255) * 32 + ((int)row & 31);
                *reinterpret_cast<u16x4*>(
                    &((unsigned short*)Dptr)[(size_t)tile * 8192 + SWZ(e)]) = o;
            } else {
                float b = bias[col];
                #pragma unroll
                for (int j = 0; j < 4; ++j)
                    ((float*)Dptr)[(row + j) * ldd + col] = v[j] + b;
            }
        }
    }
}

// ---------------- big GEMM: out += adj @ T ---------------------------------
// R12 tiles (BM=128, BN=256, BK=32, acc[4][4]); NEW deep pipeline:
// A regs 3 named stages (issue p+3, consume p+1: 2-phase cover);
// sB 3 buffers (issue p+2, consume p+1: ~1.5-phase cover); sA 2 buffers.
// Queue/phase: issue [B(p+2)x2, A(p+3)x2]; wait vmcnt(8)=A(p+1),
// vmcnt(6)=B(p+1). LDS = 2x8K + 3x16K = 64 KB -> 2 blocks/CU.
__global__ __launch_bounds__(512, 4)
void gemm_big(const float* __restrict__ A,            // adj 8192x8192 f32
              const unsigned short* __restrict__ Bt,  // Tbt [2][256][8192]
              float* __restrict__ Out) {              // 8192x512 (pre-filled)
    __shared__ unsigned short sA[2][128 * 32];   // 2 x 8 KB
    __shared__ unsigned short sB[3][256 * 32];   // 3 x 16 KB

    const int t = threadIdx.x;
    const int l = t & 63;
    const int w = t >> 6;
    const int wm = w & 1;        // 2 m-waves (64 rows)
    const int wn = w >> 1;       // 4 n-waves (64 cols)

    const int lin = blockIdx.x;          // 0..511
    const int xcd = lin & 7;
    const int idx = lin >> 3;            // 0..63
    const int mt = xcd * 8 + (idx & 7);  // mt-octet per XCD
    const int rest = idx >> 3;           // 0..7
    const int nt = rest & 1;
    const int kq = rest >> 1;            // 0..3

    const long m0 = (long)mt * 128;
    const long k0 = (long)kq * 2048;
    const int ktb = nt * 256 + kq * 64;  // base 32k-tile index in Tbt
    constexpr int P = 64;                // phases of BK=32

    f32x4 acc[4][4];
    #pragma unroll
    for (int mi = 0; mi < 4; ++mi)
        #pragma unroll
        for (int ni = 0; ni < 4; ++ni)
            acc[mi][ni] = {0.f, 0.f, 0.f, 0.f};

    // three NAMED A register stages (rule #20); A(p) lives in stage p%3
    f32x4 a00, a01, a10, a11, a20, a21;

    auto gll_B = [&](int p, int buf) {
        const unsigned short* src = Bt + (size_t)(ktb + p) * 8192 + t * 8;
        #pragma unroll
        for (int r = 0; r < 2; ++r)
            __builtin_amdgcn_global_load_lds(
                (const __attribute__((address_space(1))) void*)(src + r * 4096),
                (__attribute__((address_space(3))) void*)&sB[buf][r * 4096 + w * 512],
                16, 0, 0);
    };

    auto load_A = [&](int p, f32x4& x0, f32x4& x1) {
        const float* base = A + m0 * 8192 + k0 + (long)p * 32;
        const float* p0 = base + (long)(t >> 3) * 8192 + ((t & 7) << 2);
        const float* p1 = base + (long)(64 + (t >> 3)) * 8192 + ((t & 7) << 2);
        asm volatile("global_load_dwordx4 %0, %2, off\n\t"
                     "global_load_dwordx4 %1, %3, off"
                     : "=&v"(x0), "=&v"(x1)
                     : "v"(p0), "v"(p1)
                     : "memory");
    };

    auto write_A = [&](int buf, const f32x4& x0, const f32x4& x1) {
        int e0 = (t >> 3) * 32 + ((t & 7) << 2);
        int e1 = (64 + (t >> 3)) * 32 + ((t & 7) << 2);
        u16x4 w0 = {f2bf(x0[0]), f2bf(x0[1]), f2bf(x0[2]), f2bf(x0[3])};
        *reinterpret_cast<u16x4*>(&sA[buf][SWZ(e0)]) = w0;
        u16x4 w1 = {f2bf(x1[0]), f2bf(x1[1]), f2bf(x1[2]), f2bf(x1[3])};
        *reinterpret_cast<u16x4*>(&sA[buf][SWZ(e1)]) = w1;
    };

    auto compute = [&](int bufA, int bufB) {
        const int kb = (l >> 4) << 3;           // 0/8/16/24
        bf16x8 af[4], bfr[4];
        #pragma unroll
        for (int mi = 0; mi < 4; ++mi) {
            int row = wm * 64 + mi * 16 + (l & 15);
            af[mi] = *reinterpret_cast<const bf16x8*>(&sA[bufA][SWZ(row * 32 + kb)]);
        }
        #pragma unroll
        for (int ni = 0; ni < 4; ++ni) {
            int col = wn * 64 + ni * 16 + (l & 15);
            bfr[ni] = *reinterpret_cast<const bf16x8*>(&sB[bufB][SWZ(col * 32 + kb)]);
        }
        __builtin_amdgcn_s_setprio(1);
        #pragma unroll
        for (int mi = 0; mi < 4; ++mi)
            #pragma unroll
            for (int ni = 0; ni < 4; ++ni)
                acc[mi][ni] = __builtin_amdgcn_mfma_f32_16x16x32_bf16(
                    af[mi], bfr[ni], acc[mi][ni], 0, 0, 0);
        __builtin_amdgcn_s_setprio(0);
    };

    // ---- prologue: establish Q_0 = [A(1)2, B(1)2, A(2)2],
    //      sA[0]=tile0, sB[0]=tile0 ----
    load_A(0, a00, a01);                               // A0
    gll_B(0, 0);                                       // +B0 = 4
    asm volatile("s_waitcnt vmcnt(2)" ::: "memory");   // A(0) landed
    __builtin_amdgcn_sched_barrier(0);
    write_A(0, a00, a01);
    load_A(1, a10, a11);                               // B0,A1
    gll_B(1, 1);                                       // +B1
    load_A(2, a20, a21);                               // +A2 = 8
    asm volatile("s_waitcnt vmcnt(6) lgkmcnt(0)" ::: "memory");  // B(0) in
    __builtin_amdgcn_s_barrier();
    __builtin_amdgcn_sched_barrier(0);

    // phase body: issue B(p+2)->sB[BB], A(p+3)->stage(p%3);
    // wait A(p+1) [vmcnt 8]; write -> sA[SAW]; compute(sA[SAC], sB[BC]);
    // wait B(p+1) [vmcnt 6]; barrier.
#define PHASE_FULL(Pexpr, SAW, SAC, BB, BC, L0, L1, W0, W1)                   \
    gll_B((Pexpr) + 2, BB);                                                   \
    load_A((Pexpr) + 3, L0, L1);                                              \
    asm volatile("s_waitcnt vmcnt(8)" ::: "memory");                          \
    __builtin_amdgcn_sched_barrier(0);                                        \
    write_A(SAW, W0, W1);                                                     \
    compute(SAC, BC);                                                         \
    asm volatile("s_waitcnt vmcnt(6) lgkmcnt(0)" ::: "memory");               \
    __builtin_amdgcn_s_barrier();                                             \
    __builtin_amdgcn_sched_barrier(0);

    // main loop: p = 0..59, unrolled x6 (sA parity 2 x stage mod 3)
    for (int p = 0; p < P - 4; p += 6) {
        PHASE_FULL(p + 0, 1, 0, 2, 0, a00, a01, a10, a11)
        PHASE_FULL(p + 1, 0, 1, 0, 1, a10, a11, a20, a21)
        PHASE_FULL(p + 2, 1, 0, 1, 2, a20, a21, a00, a01)
        PHASE_FULL(p + 3, 0, 1, 2, 0, a00, a01, a10, a11)
        PHASE_FULL(p + 4, 1, 0, 0, 1, a10, a11, a20, a21)
        PHASE_FULL(p + 5, 0, 1, 1, 2, a20, a21, a00, a01)
    }
#undef PHASE_FULL

    // ---- tails (P=64): p=60 full (pattern j0), 61, 62, 63 ----
    // p=60: c0=0
    gll_B(62, 2);
    load_A(63, a00, a01);
    asm volatile("s_waitcnt vmcnt(8)" ::: "memory");   // A(61)
    __builtin_amdgcn_sched_barrier(0);
    write_A(1, a10, a11);
    compute(0, 0);
    asm volatile("s_waitcnt vmcnt(6) lgkmcnt(0)" ::: "memory");  // B(61)
    __builtin_amdgcn_s_barrier();
    __builtin_amdgcn_sched_barrier(0);

    // p=61: issue only gll_B(63); Q=[A62,B62,A63,B63]=8
    gll_B(63, 0);
    asm volatile("s_waitcnt vmcnt(6)" ::: "memory");   // A(62)
    __builtin_amdgcn_sched_barrier(0);
    write_A(0, a20, a21);
    compute(1, 1);
    asm volatile("s_waitcnt vmcnt(4) lgkmcnt(0)" ::: "memory");  // B(62)
    __builtin_amdgcn_s_barrier();
    __builtin_amdgcn_sched_barrier(0);

    // p=62: no issues; Q=[A63,B63]
    asm volatile("s_waitcnt vmcnt(2)" ::: "memory");   // A(63)
    __builtin_amdgcn_sched_barrier(0);
    write_A(1, a00, a01);
    compute(0, 2);
    asm volatile("s_waitcnt vmcnt(0) lgkmcnt(0)" ::: "memory");  // B(63)
    __builtin_amdgcn_s_barrier();
    __builtin_amdgcn_sched_barrier(0);

    // p=63
    compute(1, 0);

    // epilogue: atomic accumulate into pre-filled Out
    #pragma unroll
    for (int mi = 0; mi < 4; ++mi) {
        const long row0 = m0 + wm * 64 + mi * 16 + ((l >> 4) << 2);
        #pragma unroll
        for (int ni = 0; ni < 4; ++ni) {
            const int col = nt * 256 + wn * 64 + ni * 16 + (l & 15);
            #pragma unroll
            for (int j = 0; j < 4; ++j)
                unsafeAtomicAdd(&Out[(row0 + j) * 512 + col], acc[mi][ni][j]);
        }
    }
}

extern "C" void kernel_launch(void* const* d_in, const int* in_sizes, int n_in,
                              void* d_out, int out_size, void* d_ws, size_t ws_size,
                              hipStream_t stream) {
    const float* input  = (const float*)d_in[0];   // 8192 x 512
    const float* adj    = (const float*)d_in[1];   // 8192 x 8192
    const float* x      = (const float*)d_in[2];   // 8192 x 512
    const float* weight = (const float*)d_in[3];   // 9216 x 512
    const float* bias   = (const float*)d_in[4];   // 512

    const int N = 8192, IN_F = 512, NFEAT = 512, OUT_F = 512;
    float* out = (float*)d_out;

    // workspace (~9.5 MB): Tbt [2 nt][256 kt32][8192], W1t/W3t [4][8][8192]
    unsigned short* Tbt = (unsigned short*)d_ws;
    unsigned short* W1t = Tbt + (size_t)OUT_F * N;
    unsigned short* W3t = W1t + (size_t)OUT_F * IN_F;

    transpose_cvt<<<dim3((IN_F * OUT_F) / 256), dim3(256), 0, stream>>>(
        weight, W1t, IN_F, OUT_F);
    transpose_cvt<<<dim3((NFEAT * OUT_F) / 256), dim3(256), 0, stream>>>(
        weight + (size_t)(IN_F + N) * OUT_F, W3t, NFEAT, OUT_F);

    dim3 grid(OUT_F / 128, N / 64);   // (4, 128) = 512 blocks

    // out = x @ W3 + bias   (pre-fill for big-GEMM atomics)
    gemm_small<1><<<grid, 512, 0, stream>>>(
        x, (long)NFEAT, W3t, NFEAT,
        nullptr, 0, bias,
        out, (long)OUT_F);

    // Tbt = (input @ W1 + W2) as 256x32 LDS-image tiles
    gemm_small<0><<<grid, 512, 0, stream>>>(
        input, (long)IN_F, W1t, IN_F,
        weight + (size_t)IN_F * OUT_F, (long)OUT_F, nullptr,
        Tbt, 0);

    // out += adj @ T
    gemm_big<<<dim3(512), dim3(512), 0, stream>>>(adj, Tbt, out);
}